// Round 2
// baseline (381.060 us; speedup 1.0000x reference)
//
#include <hip/hip_runtime.h>
#include <hip/hip_bf16.h>

#define NN   100000
#define NE   1600000
#define FIN  256
#define HID  32
#define OUTD 16
#define NBLK ((NN + 255) / 256)   // 391 scan blocks

#define BM          256
#define GEMM_BLOCKS ((NN + BM - 1) / BM)                 // 391
#define CNT_EDGES   2048
#define CNT_BLOCKS  ((NE + CNT_EDGES - 1) / CNT_EDGES)   // 782
#define FUSE_BLOCKS (GEMM_BLOCKS + CNT_BLOCKS)           // 1173
#define FILL_BLOCKS ((NE + 1023) / 1024)                 // 1563

// ---- workspace layout (32-bit word offsets) ----
#define OFF_FLAG    0                      // [0]=is64, [1]=isf32
#define OFF_DEG     64                     // NN u32 packed (count<<26 | wsum*2^20)
#define OFF_DINV    (OFF_DEG + NN)         // NN floats
#define OFF_RANK    (OFF_DINV + NN)        // NE ints
#define OFF_BSUM    (OFF_RANK + NE)        // 512 ints (+512 pad)
#define OFF_ROWPTR  (OFF_BSUM + 1024)      // NN+1 ints
#define OFF_CSR     (OFF_ROWPTR + NN + 32) // 2*NE words (int2 pairs), 8B-aligned
#define OFF_H1      (OFF_CSR + 2*NE)       // NN*HID floats
#define OFF_P2      (OFF_H1 + NN*HID)      // NN*OUTD floats

#define CSHIFT 26
#define CMASK  ((1u << CSHIFT) - 1u)
#define WSCALE 1048576.0f                  // 2^20
#define WINV   (1.0f / 1048576.0f)

__device__ __forceinline__ float bf2f(unsigned short u) {
  union { unsigned int i; float f; } v; v.i = ((unsigned int)u) << 16; return v.f;
}
__device__ __forceinline__ unsigned short f2bf(float f) {
  union { float f; unsigned int i; } v; v.f = f;
  unsigned int x = v.i;
  return (unsigned short)((x + 0x7fffu + ((x >> 16) & 1u)) >> 16); // RNE
}
__device__ __forceinline__ int eidx(const int* __restrict__ ei, long long pos, int is64) {
  return is64 ? ei[2 * pos] : ei[pos];
}
__device__ __forceinline__ float ldf(const void* p, long long i, int isf32) {
  return isf32 ? ((const float*)p)[i] : bf2f(((const unsigned short*)p)[i]);
}

// ---- K0: detect flags (block 0) + zero deg (blocks 1..) ----
__global__ __launch_bounds__(256) void detect_zero_kernel(const int* __restrict__ ei,
    const unsigned short* __restrict__ xu, int* __restrict__ flags,
    unsigned int* __restrict__ zp, int zn) {
  int b = blockIdx.x;
  if (b == 0) {
    __shared__ int any, cnt;
    if (threadIdx.x == 0) { any = 0; cnt = 0; }
    __syncthreads();
    int local = 0, c = 0;
    for (int i = threadIdx.x; i < 2048; i += 256) local |= ei[2 * i + 1];
    for (int i = threadIdx.x; i < 1024; i += 256) {
      unsigned int e = (xu[2 * i] >> 7) & 0xFF;
      c += (e < 100 || e > 140) ? 1 : 0;
    }
    if (local) atomicOr(&any, 1);
    atomicAdd(&cnt, c);
    __syncthreads();
    if (threadIdx.x == 0) {
      flags[0] = (any == 0) ? 1 : 0;   // 1 => int64 layout
      flags[1] = (cnt > 100) ? 1 : 0;  // 1 => f32 floats
    }
  } else {
    int stride = (gridDim.x - 1) * 256;
    for (int i = (b - 1) * 256 + threadIdx.x; i < zn; i += stride) zp[i] = 0u;
  }
}

// ---- K1 FUSED: count_rank (u32 atomics, ILP=8) + gemm1 (256-row tile, 8x4 regs) ----
// Blocks with b%3<2 are count blocks (782); b%3==2 are gemm blocks (391).
// LDS = 32KB xs + 4.6KB wl = 37.4KB -> 4 blocks/CU (16 waves).
__global__ __launch_bounds__(256, 4) void count_gemm_kernel(const int* __restrict__ ei,
    const void* __restrict__ ew, unsigned int* __restrict__ deg,
    int* __restrict__ rank, const void* __restrict__ x,
    const void* __restrict__ W1, float* __restrict__ h1,
    const int* __restrict__ flags) {
  __shared__ float xs[32][BM];     // 32 KB, [kk][row]: bank = row%32
  __shared__ float wl[32][36];     // 4.6 KB, padded: float4 reads span all banks
  int b = blockIdx.x;
  int t = threadIdx.x;

  if ((b % 3) < 2) {
    // ---- count_rank: 8 edges/thread, u32 packed atomic ----
    int cid = (b / 3) * 2 + (b % 3);         // bijective onto 0..CNT_BLOCKS-1
    int is64 = flags[0], isf32 = flags[1];
    int e0 = cid * CNT_EDGES + t;
    int c[8]; float w[8];
    #pragma unroll
    for (int q = 0; q < 8; q++) {
      int e = e0 + q * 256;
      if (e < NE) {
        c[q] = eidx(ei, (long long)NE + e, is64);
        w[q] = ldf(ew, e, isf32);
      } else c[q] = -1;
    }
    unsigned int old[8];
    #pragma unroll
    for (int q = 0; q < 8; q++) {
      if (c[q] >= 0) {
        unsigned int inc = (1u << CSHIFT) | (unsigned int)(w[q] * WSCALE + 0.5f);
        old[q] = atomicAdd(deg + c[q], inc);
      }
    }
    #pragma unroll
    for (int q = 0; q < 8; q++)
      if (c[q] >= 0) rank[e0 + q * 256] = (int)(old[q] >> CSHIFT);
    return;
  }

  // ---- gemm1: h1 = x @ W1. 256 rows/block, thread tile 8 rows x 4 cols ----
  int gid = b / 3;
  int rb = gid * BM;
  int isf32 = flags[1];

  int rowg = t >> 3, colg = t & 7;
  int r0 = rowg * 8, m0 = colg * 4;
  int srow = t >> 1;                 // staging row 0..127 (and +128)
  int kk0s = (t & 1) * 16;           // staging k half
  int kkw = t >> 3, mw = (t & 7) * 4; // W staging role

  float acc[8][4];
  #pragma unroll
  for (int i = 0; i < 8; i++)
    #pragma unroll
    for (int j = 0; j < 4; j++) acc[i][j] = 0.f;

  union Pf { uint4 u[4]; float f[16]; unsigned short s[32]; };
  Pf pfx[2];
  uint4 pw;

  // --- prefetch helpers (macros keep everything in registers) ---
#define LOADX(rblk, kc_) do {                                                  \
    int row_ = srow + (rblk) * 128;                                            \
    long long g_ = (long long)rb + row_;                                       \
    if (g_ < NN) {                                                             \
      if (isf32) {                                                             \
        const float* xp_ = (const float*)x + g_ * FIN + (kc_) + kk0s;          \
        pfx[rblk].u[0] = ((const uint4*)xp_)[0];                               \
        pfx[rblk].u[1] = ((const uint4*)xp_)[1];                               \
        pfx[rblk].u[2] = ((const uint4*)xp_)[2];                               \
        pfx[rblk].u[3] = ((const uint4*)xp_)[3];                               \
      } else {                                                                 \
        const unsigned short* xp_ = (const unsigned short*)x + g_ * FIN + (kc_) + kk0s; \
        pfx[rblk].u[0] = ((const uint4*)xp_)[0];                               \
        pfx[rblk].u[1] = ((const uint4*)xp_)[1];                               \
      }                                                                        \
    }                                                                          \
  } while (0)

#define STOREX(rblk) do {                                                      \
    int row_ = srow + (rblk) * 128;                                            \
    bool ok_ = ((long long)rb + row_) < NN;                                    \
    if (isf32) {                                                               \
      _Pragma("unroll")                                                        \
      for (int q = 0; q < 16; q++) xs[kk0s + q][row_] = ok_ ? pfx[rblk].f[q] : 0.f; \
    } else {                                                                   \
      _Pragma("unroll")                                                        \
      for (int q = 0; q < 16; q++) xs[kk0s + q][row_] = ok_ ? bf2f(pfx[rblk].s[q]) : 0.f; \
    }                                                                          \
  } while (0)

#define LOADW(kc_) do {                                                        \
    if (isf32) {                                                               \
      pw = *(const uint4*)((const float*)W1 + ((kc_) + kkw) * HID + mw);       \
    } else {                                                                   \
      const unsigned short* wp_ = (const unsigned short*)W1 + ((kc_) + kkw) * HID + mw; \
      pw.x = ((const unsigned int*)wp_)[0];                                    \
      pw.y = ((const unsigned int*)wp_)[1];                                    \
    }                                                                          \
  } while (0)

#define STOREW() do {                                                          \
    if (isf32) {                                                               \
      *(float4*)&wl[kkw][mw] = *(float4*)&pw;                                  \
    } else {                                                                   \
      const unsigned short* ps_ = (const unsigned short*)&pw;                  \
      wl[kkw][mw + 0] = bf2f(ps_[0]); wl[kkw][mw + 1] = bf2f(ps_[1]);          \
      wl[kkw][mw + 2] = bf2f(ps_[2]); wl[kkw][mw + 3] = bf2f(ps_[3]);          \
    }                                                                          \
  } while (0)

  LOADX(0, 0); LOADX(1, 0); LOADW(0);

  for (int kc = 0; kc < FIN; kc += 32) {
    __syncthreads();                 // xs/wl free (previous compute done)
    STOREX(0); STOREX(1); STOREW();
    __syncthreads();
    if (kc + 32 < FIN) { LOADX(0, kc + 32); LOADX(1, kc + 32); LOADW(kc + 32); }
    #pragma unroll 8
    for (int kk = 0; kk < 32; kk++) {
      float4 xa = *(const float4*)&xs[kk][r0];
      float4 xb = *(const float4*)&xs[kk][r0 + 4];
      float4 wv = *(const float4*)&wl[kk][m0];
      float xr[8] = {xa.x, xa.y, xa.z, xa.w, xb.x, xb.y, xb.z, xb.w};
      float wr[4] = {wv.x, wv.y, wv.z, wv.w};
      #pragma unroll
      for (int i = 0; i < 8; i++)
        #pragma unroll
        for (int j = 0; j < 4; j++)
          acc[i][j] = fmaf(xr[i], wr[j], acc[i][j]);
    }
  }

  #pragma unroll
  for (int i = 0; i < 8; i++) {
    int g = rb + r0 + i;
    if (g < NN) {
      float4 v; v.x = acc[i][0]; v.y = acc[i][1]; v.z = acc[i][2]; v.w = acc[i][3];
      *(float4*)(h1 + (long long)g * HID + m0) = v;
    }
  }
#undef LOADX
#undef STOREX
#undef LOADW
#undef STOREW
}

// ---- K2 FUSED: scan_sum (blocks 0..390) + dinv (blocks 391..781) ----
__global__ __launch_bounds__(256) void dinv_scansum_kernel(
    const unsigned int* __restrict__ deg, float* __restrict__ dinv,
    int* __restrict__ bsum) {
  int b = blockIdx.x;
  if (b < NBLK) {
    __shared__ int s[256];
    int i = b * 256 + threadIdx.x;
    s[threadIdx.x] = (i < NN) ? (int)(deg[i] >> CSHIFT) : 0;
    __syncthreads();
    for (int off = 128; off > 0; off >>= 1) {
      if (threadIdx.x < off) s[threadIdx.x] += s[threadIdx.x + off];
      __syncthreads();
    }
    if (threadIdx.x == 0) bsum[b] = s[0];
  } else {
    int i = (b - NBLK) * 256 + threadIdx.x;
    if (i >= NN) return;
    float d = (float)(deg[i] & CMASK) * WINV + 1.0f;  // + self-loop
    dinv[i] = rsqrtf(d);
  }
}

// ---- scan: write rowptr; each block reduces bsum prefix itself ----
__global__ __launch_bounds__(256) void scan_write_kernel(const unsigned int* __restrict__ deg,
    const int* __restrict__ bsum, int* __restrict__ rowptr) {
  __shared__ int a[256];
  __shared__ int base_s;
  int t = threadIdx.x;
  int b = blockIdx.x;
  int v = 0;
  for (int i = t; i < NBLK; i += 256) v += (i < b) ? bsum[i] : 0;
  a[t] = v;
  __syncthreads();
  for (int off = 128; off > 0; off >>= 1) {
    if (t < off) a[t] += a[t + off];
    __syncthreads();
  }
  if (t == 0) base_s = a[0];
  __syncthreads();
  int base = base_s;
  int i = b * 256 + t;
  int orig = (i < NN) ? (int)(deg[i] >> CSHIFT) : 0;
  a[t] = orig;
  __syncthreads();
  for (int off = 1; off < 256; off <<= 1) {
    int x2 = a[t] + ((t >= off) ? a[t - off] : 0);
    __syncthreads();
    a[t] = x2;
    __syncthreads();
  }
  if (i < NN) rowptr[i] = base + a[t] - orig;  // exclusive
  if (b == 0 && t == 0) rowptr[NN] = NE;
}

// ---- fill CSR: (src, norm) pairs bucketed by dst — NO atomics, 4 edges/thread ----
__global__ __launch_bounds__(256) void fill_csr_kernel(const int* __restrict__ ei,
    const void* __restrict__ ew, const float* __restrict__ dinv,
    const int* __restrict__ rowptr, const int* __restrict__ rank,
    int2* __restrict__ csr, const int* __restrict__ flags) {
  int is64 = flags[0], isf32 = flags[1];
  int e0 = blockIdx.x * 1024 + threadIdx.x;
  int r[4], c[4], rk[4]; float w[4];
  #pragma unroll
  for (int q = 0; q < 4; q++) {
    int e = e0 + q * 256;
    if (e < NE) {
      r[q]  = eidx(ei, e, is64);
      c[q]  = eidx(ei, (long long)NE + e, is64);
      w[q]  = ldf(ew, e, isf32);
      rk[q] = rank[e];
    } else c[q] = -1;
  }
  float dr[4], dc[4]; int rp[4];
  #pragma unroll
  for (int q = 0; q < 4; q++) {
    if (c[q] >= 0) {
      dr[q] = dinv[r[q]];
      dc[q] = dinv[c[q]];
      rp[q] = rowptr[c[q]];
    }
  }
  #pragma unroll
  for (int q = 0; q < 4; q++) {
    if (c[q] >= 0) {
      int2 pr; pr.x = r[q]; pr.y = __float_as_int(dr[q] * w[q] * dc[q]);
      csr[rp[q] + rk[q]] = pr;
    }
  }
}

// ---- gather1 fused: conv1 aggregate + self-loop + bias + ReLU + @W2 -> p2 ----
__global__ __launch_bounds__(256) void gather1_kernel(const float* __restrict__ h1,
    const float* __restrict__ dinv, const int* __restrict__ rowptr,
    const int2* __restrict__ csr, const void* __restrict__ b1,
    const void* __restrict__ W2, float* __restrict__ p2,
    const int* __restrict__ flags) {
  __shared__ float w2lds[HID * OUTD];  // [k][m] flat
  __shared__ float b1l[HID];
  __shared__ float tl[8][HID + 1];
  int t = threadIdx.x;
  int isf32 = flags[1];
  w2lds[2 * t]     = ldf(W2, 2 * t, isf32);
  w2lds[2 * t + 1] = ldf(W2, 2 * t + 1, isf32);
  if (t < HID) b1l[t] = ldf(b1, t, isf32);
  __syncthreads();

  int nl = t >> 5;          // node slot 0..7
  int j  = t & 31;          // feature
  int node = blockIdx.x * 8 + nl;
  if (node < NN) {
    int k0 = rowptr[node], k1 = rowptr[node + 1];
    float acc = 0.f;
    int k = k0;
    for (; k + 8 <= k1; k += 8) {
      int2 q0 = csr[k];     int2 q1 = csr[k + 1];
      int2 q2 = csr[k + 2]; int2 q3 = csr[k + 3];
      int2 q4 = csr[k + 4]; int2 q5 = csr[k + 5];
      int2 q6 = csr[k + 6]; int2 q7 = csr[k + 7];
      float v0 = h1[q0.x * HID + j]; float v1 = h1[q1.x * HID + j];
      float v2 = h1[q2.x * HID + j]; float v3 = h1[q3.x * HID + j];
      float v4 = h1[q4.x * HID + j]; float v5 = h1[q5.x * HID + j];
      float v6 = h1[q6.x * HID + j]; float v7 = h1[q7.x * HID + j];
      acc = fmaf(__int_as_float(q0.y), v0, acc);
      acc = fmaf(__int_as_float(q1.y), v1, acc);
      acc = fmaf(__int_as_float(q2.y), v2, acc);
      acc = fmaf(__int_as_float(q3.y), v3, acc);
      acc = fmaf(__int_as_float(q4.y), v4, acc);
      acc = fmaf(__int_as_float(q5.y), v5, acc);
      acc = fmaf(__int_as_float(q6.y), v6, acc);
      acc = fmaf(__int_as_float(q7.y), v7, acc);
    }
    for (; k + 4 <= k1; k += 4) {
      int2 q0 = csr[k];     int2 q1 = csr[k + 1];
      int2 q2 = csr[k + 2]; int2 q3 = csr[k + 3];
      float v0 = h1[q0.x * HID + j]; float v1 = h1[q1.x * HID + j];
      float v2 = h1[q2.x * HID + j]; float v3 = h1[q3.x * HID + j];
      acc = fmaf(__int_as_float(q0.y), v0, acc);
      acc = fmaf(__int_as_float(q1.y), v1, acc);
      acc = fmaf(__int_as_float(q2.y), v2, acc);
      acc = fmaf(__int_as_float(q3.y), v3, acc);
    }
    for (; k < k1; k++) {
      int2 pr = csr[k];
      acc = fmaf(__int_as_float(pr.y), h1[pr.x * HID + j], acc);
    }
    float di = dinv[node];
    acc = fmaf(di * di, h1[node * HID + j], acc);
    acc += b1l[j];
    tl[nl][j] = fmaxf(acc, 0.f);
  }
  __syncthreads();
  int m = t & 31;
  if (node < NN && m < OUTD) {
    float s = 0.f;
    #pragma unroll
    for (int k = 0; k < HID; k++) s = fmaf(tl[nl][k], w2lds[k * OUTD + m], s);
    p2[node * OUTD + m] = s;
  }
}

// ---- gather2: conv2 aggregate + self-loop + bias -> out ----
__global__ __launch_bounds__(256) void gather2_kernel(const float* __restrict__ p2,
    const float* __restrict__ dinv, const int* __restrict__ rowptr,
    const int2* __restrict__ csr, const void* __restrict__ b2,
    void* __restrict__ out, const int* __restrict__ flags) {
  __shared__ float b2l[OUTD];
  int t = threadIdx.x;
  int isf32 = flags[1];
  if (t < OUTD) b2l[t] = ldf(b2, t, isf32);
  __syncthreads();

  int nl = t >> 4;
  int m  = t & 15;
  int node = blockIdx.x * 16 + nl;
  if (node >= NN) return;
  int k0 = rowptr[node], k1 = rowptr[node + 1];
  float acc = 0.f;
  int k = k0;
  for (; k + 8 <= k1; k += 8) {
    int2 q0 = csr[k];     int2 q1 = csr[k + 1];
    int2 q2 = csr[k + 2]; int2 q3 = csr[k + 3];
    int2 q4 = csr[k + 4]; int2 q5 = csr[k + 5];
    int2 q6 = csr[k + 6]; int2 q7 = csr[k + 7];
    float v0 = p2[q0.x * OUTD + m]; float v1 = p2[q1.x * OUTD + m];
    float v2 = p2[q2.x * OUTD + m]; float v3 = p2[q3.x * OUTD + m];
    float v4 = p2[q4.x * OUTD + m]; float v5 = p2[q5.x * OUTD + m];
    float v6 = p2[q6.x * OUTD + m]; float v7 = p2[q7.x * OUTD + m];
    acc = fmaf(__int_as_float(q0.y), v0, acc);
    acc = fmaf(__int_as_float(q1.y), v1, acc);
    acc = fmaf(__int_as_float(q2.y), v2, acc);
    acc = fmaf(__int_as_float(q3.y), v3, acc);
    acc = fmaf(__int_as_float(q4.y), v4, acc);
    acc = fmaf(__int_as_float(q5.y), v5, acc);
    acc = fmaf(__int_as_float(q6.y), v6, acc);
    acc = fmaf(__int_as_float(q7.y), v7, acc);
  }
  for (; k + 4 <= k1; k += 4) {
    int2 q0 = csr[k];     int2 q1 = csr[k + 1];
    int2 q2 = csr[k + 2]; int2 q3 = csr[k + 3];
    float v0 = p2[q0.x * OUTD + m]; float v1 = p2[q1.x * OUTD + m];
    float v2 = p2[q2.x * OUTD + m]; float v3 = p2[q3.x * OUTD + m];
    acc = fmaf(__int_as_float(q0.y), v0, acc);
    acc = fmaf(__int_as_float(q1.y), v1, acc);
    acc = fmaf(__int_as_float(q2.y), v2, acc);
    acc = fmaf(__int_as_float(q3.y), v3, acc);
  }
  for (; k < k1; k++) {
    int2 pr = csr[k];
    acc = fmaf(__int_as_float(pr.y), p2[pr.x * OUTD + m], acc);
  }
  float di = dinv[node];
  acc = fmaf(di * di, p2[node * OUTD + m], acc);
  acc += b2l[m];
  int oidx = node * OUTD + m;
  if (isf32) ((float*)out)[oidx] = acc;
  else       ((unsigned short*)out)[oidx] = f2bf(acc);
}

extern "C" void kernel_launch(void* const* d_in, const int* in_sizes, int n_in,
                              void* d_out, int out_size, void* d_ws, size_t ws_size,
                              hipStream_t stream) {
  const void* x  = d_in[0];
  const int* ei  = (const int*)d_in[1];
  const void* ew = d_in[2];
  const void* W1 = d_in[3];
  const void* b1 = d_in[4];
  const void* W2 = d_in[5];
  const void* b2 = d_in[6];
  float* ws = (float*)d_ws;
  int* wsi = (int*)d_ws;
  unsigned int* deg = (unsigned int*)(wsi + OFF_DEG);

  detect_zero_kernel<<<dim3(513), dim3(256), 0, stream>>>(ei, (const unsigned short*)x,
      wsi + OFF_FLAG, deg, NN);
  count_gemm_kernel<<<dim3(FUSE_BLOCKS), dim3(256), 0, stream>>>(ei, ew, deg,
      wsi + OFF_RANK, x, W1, ws + OFF_H1, wsi + OFF_FLAG);
  dinv_scansum_kernel<<<dim3(2 * NBLK), dim3(256), 0, stream>>>(deg, ws + OFF_DINV, wsi + OFF_BSUM);
  scan_write_kernel<<<dim3(NBLK), dim3(256), 0, stream>>>(deg, wsi + OFF_BSUM, wsi + OFF_ROWPTR);
  fill_csr_kernel<<<dim3(FILL_BLOCKS), dim3(256), 0, stream>>>(ei, ew, ws + OFF_DINV,
      wsi + OFF_ROWPTR, wsi + OFF_RANK, (int2*)(wsi + OFF_CSR), wsi + OFF_FLAG);
  gather1_kernel<<<dim3((NN + 7) / 8), dim3(256), 0, stream>>>(ws + OFF_H1, ws + OFF_DINV,
      wsi + OFF_ROWPTR, (const int2*)(wsi + OFF_CSR), b1, W2, ws + OFF_P2, wsi + OFF_FLAG);
  gather2_kernel<<<dim3((NN + 15) / 16), dim3(256), 0, stream>>>(ws + OFF_P2, ws + OFF_DINV,
      wsi + OFF_ROWPTR, (const int2*)(wsi + OFF_CSR), b2, d_out, wsi + OFF_FLAG);
}